// Round 8
// baseline (109.309 us; speedup 1.0000x reference)
//
#include <hip/hip_runtime.h>
#include <math.h>

#define B_ 64
#define E_ 256
#define S_ 32
#define H_ 16
#define P_ 512
#define KC_ 46

// workspace float offsets (float4-aligned)
#define WS_WB     16384    // 98304 float-slots: Wb[768][256] bf16
#define WS_XF     114688   // 262144 float-slots: XF[32][64][256] bf16 (s,b,e)
#define WS_OPART  1949696  // 524288 O_part[32][16][64][16]  (s,h,a,d)

typedef short bf16x8 __attribute__((ext_vector_type(8)));
typedef float f32x4  __attribute__((ext_vector_type(4)));

__device__ __forceinline__ ushort f2bf(float f) {
  unsigned u = __float_as_uint(f);
  u = (u + 0x7FFFu + ((u >> 16) & 1u)) >> 16;   // RNE
  return (ushort)u;
}

__device__ __forceinline__ int pairclass(int la, int lb) {
  if (la == lb) return 0;
  int lo = la < lb ? la : lb, hi = la < lb ? lb : la;
  return 1 + lo*9 - (lo*(lo-1))/2 + (hi - lo - 1);
}

// ============ K0: prep: Wb bf16 convert | XF transpose-convert | zero ======
__global__ __launch_bounds__(256) void k_prep(
    const float* __restrict__ feat, const float* __restrict__ w,
    float* __restrict__ ws, float* __restrict__ out) {
  __shared__ float sm[8448];
  const int bid = blockIdx.x, t = threadIdx.x;
  if (bid < 24) {
    // ---- convert in_proj_w [768][256] fp32 -> Wb bf16 (straight copy) ----
    const float4* src = (const float4*)w;       // 49152 float4s
    ushort* dstW = (ushort*)(ws + WS_WB);
#pragma unroll
    for (int i = 0; i < 8; ++i) {
      int idx = bid*2048 + i*256 + t;
      float4 v = src[idx];
      ushort4 o;
      o.x = f2bf(v.x); o.y = f2bf(v.y); o.z = f2bf(v.z); o.w = f2bf(v.w);
      *(ushort4*)(dstW + (size_t)idx*4) = o;
    }
  } else if (bid < 88) {
    // ---- transpose-convert feat[b][e][s] -> XF[s][b][e] bf16 ----
    const int b = bid - 24;
    const float4* fb = (const float4*)(feat + (size_t)b*(E_*S_));
#pragma unroll
    for (int i = 0; i < 8; ++i) {
      int idx = i*256 + t; int e = idx >> 3, s4 = (idx & 7)*4;
      float4 v = fb[idx];
      sm[e*33 + s4+0] = v.x; sm[e*33 + s4+1] = v.y;
      sm[e*33 + s4+2] = v.z; sm[e*33 + s4+3] = v.w;
    }
    __syncthreads();
    const int s = t >> 3, eb = (t & 7) * 32;    // lanes span e: coalesced stores
    ushort* dstX = (ushort*)(ws + WS_XF) + (size_t)s*(B_*E_) + (size_t)b*E_ + eb;
#pragma unroll
    for (int g = 0; g < 4; ++g) {
      ushort tmp[8];
#pragma unroll
      for (int u = 0; u < 8; ++u) tmp[u] = f2bf(sm[(eb + g*8 + u)*33 + s]);
      *(uint4*)(dstX + g*8) = *(uint4*)tmp;
    }
  } else {
    if (t == 0) out[0] = 0.f;
  }
}

// ============ K1: fused QKV-MFMA + weighted attention per (s,h) ============
// Wave w generates Q,K,V 16x16 C-tiles for a-tile w via mfma_16x16x32_bf16,
// stages into LDS; cm computed locally from labels1 (row-major nonzero
// truncation/padding semantics); then verified VALU softmax/PV.
__global__ __launch_bounds__(256) void k_attn(
    const float* __restrict__ bias, const float* __restrict__ fw,
    const int* __restrict__ labels1, float* __restrict__ ws) {
  __shared__ float qT[16*68], kT[16*68], vs[64*20], sc[64*68], cm[64];
  __shared__ int l1s[64], gsA[64], rjA[64], rsA[64];
  const int s = blockIdx.x >> 4, h = blockIdx.x & 15;
  const int t = threadIdx.x;
  const int w = t >> 6, L = t & 63, lane16 = L & 15, quad = L >> 4;
  const int a = t >> 2, dq = t & 3;
  // early global load of labels (latency hidden under MFMA-gen)
  int myl1 = (t < 64) ? labels1[t] : 0;
  // ---- MFMA QKV generation for a-tile w ----
  {
    const short* WB = (const short*)(ws + WS_WB);
    const short* XF = (const short*)(ws + WS_XF);
    const short* brow  = XF + (size_t)s*(B_*E_) + (size_t)(w*16 + lane16)*E_ + quad*8;
    const short* arowQ = WB + (size_t)(      h*16 + lane16)*E_ + quad*8;
    const short* arowK = WB + (size_t)(256 + h*16 + lane16)*E_ + quad*8;
    const short* arowV = WB + (size_t)(512 + h*16 + lane16)*E_ + quad*8;
    f32x4 accQ = {0.f,0.f,0.f,0.f}, accK = {0.f,0.f,0.f,0.f}, accV = {0.f,0.f,0.f,0.f};
#pragma unroll
    for (int k = 0; k < 8; ++k) {
      bf16x8 bv = *(const bf16x8*)(brow  + k*32);
      bf16x8 aq = *(const bf16x8*)(arowQ + k*32);
      bf16x8 ak = *(const bf16x8*)(arowK + k*32);
      bf16x8 av = *(const bf16x8*)(arowV + k*32);
      accQ = __builtin_amdgcn_mfma_f32_16x16x32_bf16(aq, bv, accQ, 0, 0, 0);
      accK = __builtin_amdgcn_mfma_f32_16x16x32_bf16(ak, bv, accK, 0, 0, 0);
      accV = __builtin_amdgcn_mfma_f32_16x16x32_bf16(av, bv, accV, 0, 0, 0);
    }
    float4 bq  = *(const float4*)(bias +       h*16 + quad*4);
    float4 bk  = *(const float4*)(bias + 256 + h*16 + quad*4);
    float4 bv2 = *(const float4*)(bias + 512 + h*16 + quad*4);
    const float bqa[4] = {bq.x,bq.y,bq.z,bq.w};
    const float bka[4] = {bk.x,bk.y,bk.z,bk.w};
    const float bva[4] = {bv2.x,bv2.y,bv2.z,bv2.w};
    const int ag = w*16 + lane16;
#pragma unroll
    for (int r = 0; r < 4; ++r) {
      int d = quad*4 + r;
      qT[d*68 + ag] = (accQ[r] + bqa[r]) * 0.25f;   // fold 1/sqrt(16)
      kT[d*68 + ag] =  accK[r] + bka[r];
      vs[ag*20 + d] =  accV[r] + bva[r];
    }
  }
  // ---- local cm (wave 0): group sizes, ranks, rowstart, truncation, pad ----
  if (t < 64) {
    l1s[t] = myl1;
    int gj = l1s[t];
    int gs_ = 0, rj_ = 0;
#pragma unroll 8
    for (int j2 = 0; j2 < 64; ++j2) {
      int m = (l1s[j2] == gj) ? 1 : 0;
      gs_ += m;
      if (j2 < t) rj_ += m;
    }
    gsA[t] = gs_; rjA[t] = rj_;
    int rs_ = 0;
#pragma unroll 8
    for (int i = 0; i < 64; ++i) if (i < t) rs_ += gsA[i];
    rsA[t] = rs_;
    int cnt = 0;
#pragma unroll 8
    for (int i = 0; i < 64; ++i)
      if (l1s[i] == gj && rsA[i] + rj_ < P_) ++cnt;
    int total = rsA[63] + gsA[63];
    if (t == 0 && total < P_) cnt += P_ - total;   // padding pairs -> j=0
    cm[t] = (float)cnt;
  }
  __syncthreads();
  // ---- scores: 4x4 register outer product -> sc[a][b] ----
  {
    const int ta = t & 15, tb = t >> 4;
    float sa[4][4];
#pragma unroll
    for (int r = 0; r < 4; ++r)
#pragma unroll
      for (int c = 0; c < 4; ++c) sa[r][c] = 0.f;
#pragma unroll
    for (int d = 0; d < 16; ++d) {
      float4 qv = *(float4*)(qT + d*68 + ta*4);
      float4 kv = *(float4*)(kT + d*68 + tb*4);
      float qr[4] = {qv.x,qv.y,qv.z,qv.w};
      float kc[4] = {kv.x,kv.y,kv.z,kv.w};
#pragma unroll
      for (int r = 0; r < 4; ++r)
#pragma unroll
        for (int c = 0; c < 4; ++c) sa[r][c] = fmaf(qr[r], kc[c], sa[r][c]);
    }
#pragma unroll
    for (int r = 0; r < 4; ++r)
      *(float4*)(sc + (ta*4+r)*68 + tb*4) =
          make_float4(sa[r][0], sa[r][1], sa[r][2], sa[r][3]);
  }
  __syncthreads();
  // ---- weighted softmax row a, normalized in-place in sc ----
  {
    float pv[16], cmv[16];
#pragma unroll
    for (int i4 = 0; i4 < 4; ++i4) {
      float4 v = *(float4*)(sc + a*68 + dq*16 + i4*4);
      pv[i4*4+0] = v.x; pv[i4*4+1] = v.y; pv[i4*4+2] = v.z; pv[i4*4+3] = v.w;
    }
#pragma unroll
    for (int i = 0; i < 16; ++i) cmv[i] = cm[dq*16 + i];
    float Mx = -1e30f;
#pragma unroll
    for (int i = 0; i < 16; ++i) if (cmv[i] > 0.f) Mx = fmaxf(Mx, pv[i]);
    Mx = fmaxf(Mx, __shfl_xor(Mx, 1));
    Mx = fmaxf(Mx, __shfl_xor(Mx, 2));
    float z = 0.f;
#pragma unroll
    for (int i = 0; i < 16; ++i) {
      float e = (cmv[i] > 0.f) ? cmv[i]*__expf(pv[i]-Mx) : 0.f;
      pv[i] = e; z += e;
    }
    z += __shfl_xor(z, 1);
    z += __shfl_xor(z, 2);
    float rz = 1.0f / z;
#pragma unroll
    for (int i4 = 0; i4 < 4; ++i4)
      *(float4*)(sc + a*68 + dq*16 + i4*4) =
          make_float4(pv[i4*4+0]*rz, pv[i4*4+1]*rz,
                      pv[i4*4+2]*rz, pv[i4*4+3]*rz);
  }
  __syncthreads();
  // ---- PV: wave g owns rows g*16..g*16+15; lane quad spans d ----
  {
    const int g = t >> 6, l = t & 63;
    const int ar = g*16 + (l >> 2), d4 = (l & 3)*4;
    float o0 = 0.f, o1 = 0.f, o2 = 0.f, o3 = 0.f;
#pragma unroll 4
    for (int b4 = 0; b4 < 64; b4 += 4) {
      float4 p4 = *(float4*)(sc + ar*68 + b4);
      float4 va = *(float4*)(vs + (b4+0)*20 + d4);
      float4 vb = *(float4*)(vs + (b4+1)*20 + d4);
      float4 vc = *(float4*)(vs + (b4+2)*20 + d4);
      float4 vd = *(float4*)(vs + (b4+3)*20 + d4);
      o0 = fmaf(p4.x, va.x, fmaf(p4.y, vb.x, fmaf(p4.z, vc.x, fmaf(p4.w, vd.x, o0))));
      o1 = fmaf(p4.x, va.y, fmaf(p4.y, vb.y, fmaf(p4.z, vc.y, fmaf(p4.w, vd.y, o1))));
      o2 = fmaf(p4.x, va.z, fmaf(p4.y, vb.z, fmaf(p4.z, vc.z, fmaf(p4.w, vd.z, o2))));
      o3 = fmaf(p4.x, va.w, fmaf(p4.y, vb.w, fmaf(p4.z, vc.w, fmaf(p4.w, vd.w, o3))));
    }
    const float fwS = fw[s];
    float* dst = ws + WS_OPART + (size_t)s*(H_*B_*16) + h*(B_*16) + t*4;
    *(float4*)dst = make_float4(fwS*o0, fwS*o1, fwS*o2, fwS*o3);
  }
}

// ============ K2: local pair weights + O reduce + logits + lse + CE ========
// logits = hw @ (Wout @ oh + bout*sfw + fb) + hb   (M reassociated away)
__global__ __launch_bounds__(256) void k_final(
    const float* __restrict__ ws, const int* __restrict__ labels0,
    const int* __restrict__ labels1, const float* __restrict__ wout,
    const float* __restrict__ bout, const float* __restrict__ fw,
    const float* __restrict__ fbi, const float* __restrict__ hw,
    const float* __restrict__ hb, float* __restrict__ out) {
  const int aa = blockIdx.x, t = threadIdx.x;
  __shared__ float ohs[256], hs[256], lg[64], fws[32];
  __shared__ float cls[48], wsh[48], wk[48], denf;
  __shared__ int l0s[64], l1s[64], gsA[64], rjA[64], rsA[64];
  if (t < 64) { l0s[t] = labels0[t]; l1s[t] = labels1[t]; }
  if (t < 32) fws[t] = fw[t];
  if (t < 48) { cls[t] = 0.f; wk[t] = 0.f; }
  if (t == 0) denf = 0.f;
  __syncthreads();
  if (t < 64) {           // wave 0: group sizes, in-group ranks, rowstarts
    int gj = l1s[t];
    int gs_ = 0, rj_ = 0;
#pragma unroll 8
    for (int j2 = 0; j2 < 64; ++j2) {
      int m = (l1s[j2] == gj) ? 1 : 0;
      gs_ += m;
      if (j2 < t) rj_ += m;
    }
    gsA[t] = gs_; rjA[t] = rj_;
    int rs_ = 0;
#pragma unroll 8
    for (int i = 0; i < 64; ++i) if (i < t) rs_ += gsA[i];
    rsA[t] = rs_;
  }
  __syncthreads();
  // cls over selected pairs (rank < 512, all valid)
  for (int u = 0; u < 16; ++u) {
    int idx = t*16 + u; int i = idx >> 6, j = idx & 63;
    if (l1s[i] == l1s[j] && rsA[i] + rjA[j] < P_)
      atomicAdd(&cls[pairclass(l0s[i], l0s[j])], 1.f);
  }
  __syncthreads();
  if (t < KC_) {
    float cv = cls[t];
    wsh[t] = cv > 0.f ? 1.0f/cv : 0.f;
    if (cv > 0.f) atomicAdd(&denf, 1.0f);
  }
  __syncthreads();
  if (t < 64) {           // Wk[aa][y] over this row's selected pairs
    if (l1s[t] == l1s[aa] && rsA[aa] + rjA[t] < P_) {
      int y = pairclass(l0s[aa], l0s[t]);
      atomicAdd(&wk[y], wsh[y]);
    }
  }
  // ---- reduce O_part over s for row aa ----
  {
    const float* op = ws + WS_OPART + (t>>4)*(B_*16) + aa*16 + (t&15);
    float acc = 0.f;
#pragma unroll
    for (int s = 0; s < S_; ++s) acc += op[(size_t)s*(H_*B_*16)];
    ohs[t] = acc;
  }
  __syncthreads();
  // ---- h = Wout @ oh + bout*sfw + fb ----
  {
    float sfw = 0.f;
#pragma unroll
    for (int s2 = 0; s2 < S_; ++s2) sfw += fws[s2];
    float gacc = 0.f;
    const float4* wr = (const float4*)(wout + (size_t)t*E_);
    const float4* o4 = (const float4*)ohs;
#pragma unroll 8
    for (int j = 0; j < 64; ++j) {
      float4 wv = wr[j], ov = o4[j];
      gacc = fmaf(wv.x, ov.x, gacc); gacc = fmaf(wv.y, ov.y, gacc);
      gacc = fmaf(wv.z, ov.z, gacc); gacc = fmaf(wv.w, ov.w, gacc);
    }
    hs[t] = gacc + bout[t]*sfw + fbi[0];
  }
  __syncthreads();
  // ---- logits[k] = hw[k] . h + hb[k]  (4 lanes per k) ----
  {
    const int k = t >> 2, q = t & 3;
    if (k < KC_) {
      float lv = 0.f;
      const float4* h4 = (const float4*)(hw + (size_t)k*E_ + q*64);
      const float4* s4 = (const float4*)(hs + q*64);
#pragma unroll
      for (int j = 0; j < 16; ++j) {
        float4 m = h4[j], o = s4[j];
        lv = fmaf(m.x, o.x, lv); lv = fmaf(m.y, o.y, lv);
        lv = fmaf(m.z, o.z, lv); lv = fmaf(m.w, o.w, lv);
      }
      lv += __shfl_xor(lv, 1);
      lv += __shfl_xor(lv, 2);
      if (q == 0) lg[k] = lv + hb[k];
    }
  }
  __syncthreads();
  if (t < 64) {
    float x = (t < KC_) ? lg[t] : -1e30f;
    float Mx = x;
#pragma unroll
    for (int off = 1; off < 64; off <<= 1) Mx = fmaxf(Mx, __shfl_xor(Mx, off));
    float z = (t < KC_) ? __expf(x - Mx) : 0.f;
#pragma unroll
    for (int off = 1; off < 64; off <<= 1) z += __shfl_xor(z, off);
    float lse = Mx + __logf(z);
    float term = (t < KC_) ? wk[t] * (lse - x) : 0.f;
#pragma unroll
    for (int off = 1; off < 64; off <<= 1) term += __shfl_xor(term, off);
    if (t == 0) atomicAdd(out, term / denf);
  }
}

extern "C" void kernel_launch(void* const* d_in, const int* in_sizes, int n_in,
                              void* d_out, int out_size, void* d_ws, size_t ws_size,
                              hipStream_t stream) {
  const float* feat    = (const float*)d_in[0];
  const int*   labels0 = (const int*)d_in[1];
  const int*   labels1 = (const int*)d_in[2];
  const float* ipw     = (const float*)d_in[3];
  const float* ipb     = (const float*)d_in[4];
  const float* opw     = (const float*)d_in[5];
  const float* opb     = (const float*)d_in[6];
  const float* fw      = (const float*)d_in[7];
  const float* fbi     = (const float*)d_in[8];
  const float* hw      = (const float*)d_in[9];
  const float* hb      = (const float*)d_in[10];
  float* out = (float*)d_out;
  float* ws  = (float*)d_ws;

  k_prep<<<89, 256, 0, stream>>>(feat, ipw, ws, out);
  k_attn<<<512, 256, 0, stream>>>(ipb, fw, labels1, ws);
  k_final<<<64, 256, 0, stream>>>(ws, labels0, labels1, opw, opb, fw, fbi,
                                  hw, hb, out);
}